// Round 2
// baseline (1675.351 us; speedup 1.0000x reference)
//
#include <hip/hip_runtime.h>
#include <hip/hip_bf16.h>
#include <cstdint>
#include <cstddef>

#define B_ 2
#define L_ 2048
#define D_ 512
#define H_ 8
#define HD_ 64

__device__ __forceinline__ float dot4f(float4 a, float4 b) {
  return a.x*b.x + a.y*b.y + a.z*b.z + a.w*b.w;
}

// ---------------- batched transpose of the five 512x512 weight matrices ----------------
struct TPtrs { const float* in[5]; float* out[5]; };

__global__ __launch_bounds__(256) void k_transpose5(TPtrs p) {
  __shared__ float tile[32][33];
  const float* in = p.in[blockIdx.z];
  float* out = p.out[blockIdx.z];
  int x = blockIdx.x*32 + threadIdx.x;
  int y = blockIdx.y*32 + threadIdx.y;
  #pragma unroll
  for (int j = 0; j < 32; j += 8) tile[threadIdx.y+j][threadIdx.x] = in[(size_t)(y+j)*D_ + x];
  __syncthreads();
  x = blockIdx.y*32 + threadIdx.x;
  y = blockIdx.x*32 + threadIdx.y;
  #pragma unroll
  for (int j = 0; j < 32; j += 8) out[(size_t)(y+j)*D_ + x] = tile[threadIdx.x][threadIdx.y+j];
}

// ---------------- column stats (mean over L, sum diff^2) ----------------
// stage A: 32 chunks of 64 rows; deterministic partials
__global__ __launch_bounds__(256) void k_colstats_a(const float* __restrict__ x, float* __restrict__ ps, float* __restrict__ pq) {
  int idx = blockIdx.x*256 + threadIdx.x;       // 32 * B * D = 32768
  int c   = idx >> 10;                          // chunk 0..31
  int rem = idx & 1023;                         // b*D + d
  int b = rem >> 9, d = rem & 511;
  const float* p = x + ((size_t)b*L_ + (size_t)c*64)*D_ + d;
  float s = 0.f, q = 0.f, prev;
  if (c == 0) {
    prev = p[0]; s = prev;
    for (int i = 1; i < 64; ++i) { float v = p[(size_t)i*D_]; float df = v - prev; q += df*df; s += v; prev = v; }
  } else {
    prev = *(p - D_);
    for (int i = 0; i < 64; ++i) { float v = p[(size_t)i*D_]; float df = v - prev; q += df*df; s += v; prev = v; }
  }
  ps[idx] = s; pq[idx] = q;
}
__global__ __launch_bounds__(256) void k_colstats_b(const float* __restrict__ x, const float* __restrict__ ps,
    const float* __restrict__ pq, float* __restrict__ colmean, float* __restrict__ colssq, float* __restrict__ coldiff) {
  int rem = blockIdx.x*256 + threadIdx.x;       // b*D + d, 1024 total
  if (rem >= B_*D_) return;
  int b = rem >> 9, d = rem & 511;
  float s = 0.f, q = 0.f;
  for (int c = 0; c < 32; ++c) { s += ps[c*1024 + rem]; q += pq[c*1024 + rem]; }
  colmean[rem] = s / (float)L_;
  colssq[rem]  = q;
  coldiff[rem] = x[((size_t)b*L_ + (L_-1))*D_ + d] - x[((size_t)b*L_)*D_ + d];
}

// ---------------- per-row stats ----------------
__global__ __launch_bounds__(256) void k_rowstats(const float* __restrict__ x, const float* __restrict__ colmean,
    float* __restrict__ rowmean, float* __restrict__ rowrstd, float* __restrict__ impre, float* __restrict__ tip,
    float* __restrict__ dmean, float* __restrict__ d1a, float* __restrict__ maga, float* __restrict__ wvm)
{
  const int row = blockIdx.x;            // b*L + i
  const int b = row / L_, i = row % L_;
  const int t = threadIdx.x;
  float sx=0, sxx=0, a1=0, a2=0, a3=0, a4=0, a5=0, tp=0, wv=0;
  const float* xb = x + (size_t)b*L_*D_;
  for (int d = t; d < D_; d += 256) {
    float r[8]; bool vl[8];
    #pragma unroll
    for (int k = 0; k < 8; ++k) {
      int p = i + k - 2;
      vl[k] = (p >= 0 && p < L_);
      r[k] = vl[k] ? xb[(size_t)p*D_ + d] : 0.f;
    }
    float xc = r[2];
    sx += xc; sxx += xc*xc;
    if (i+1 < L_) { a1 += fabsf(r[3]-xc); tp += fabsf(r[3] - colmean[b*D_+d]); }
    if (i+2 < L_) a2 += fabsf(r[4]-xc);
    if (i+3 < L_) a3 += fabsf(r[5]-xc);
    if (i+4 < L_) a4 += fabsf(r[6]-xc);
    if (i+5 < L_) a5 += fabsf(r[7]-xc);
    float wsum = 0.f; int n = 0;
    #pragma unroll
    for (int k = 0; k < 5; ++k) if (vl[k]) { wsum += r[k]; n++; }
    float wm = wsum / (float)n;
    float wq = 0.f;
    #pragma unroll
    for (int k = 0; k < 5; ++k) if (vl[k]) { float dv = r[k]-wm; wq += dv*dv; }
    wv += wq / (float)(n-1);
  }
  float vals[9] = {sx, sxx, a1, a2, a3, a4, a5, tp, wv};
  __shared__ float sm[9][4];
  int lane = t & 63, w = t >> 6;
  #pragma unroll
  for (int q = 0; q < 9; ++q) {
    float v = vals[q];
    #pragma unroll
    for (int o = 32; o; o >>= 1) v += __shfl_down(v, o);
    if (lane == 0) sm[q][w] = v;
  }
  __syncthreads();
  if (t == 0) {
    float S[9];
    #pragma unroll
    for (int q = 0; q < 9; ++q) S[q] = sm[q][0]+sm[q][1]+sm[q][2]+sm[q][3];
    float m  = S[0]/(float)D_;
    float var = S[1]/(float)D_ - m*m;
    rowmean[row] = m;
    rowrstd[row] = 1.0f/sqrtf(var + 1e-5f);
    maga[row] = sqrtf(S[1]);
    float d1 = S[2]/(float)D_;
    d1a[row] = d1;
    impre[row] = 0.5f*d1 + 0.3f*(S[3]/(float)D_)*0.5f + 0.2f*(S[5]/(float)D_)*0.25f;
    dmean[row] = 0.4f*d1 + 0.3f*(S[3]/(float)D_)*0.5f + 0.2f*(S[4]/(float)D_)*(1.f/3.f) + 0.1f*(S[6]/(float)D_)*0.2f;
    tip[row] = S[7]/(float)D_;
    wvm[row] = S[8]/(float)D_;
  }
}

// ---------------- per-batch stats ----------------
__global__ __launch_bounds__(256) void k_batchstats(const float* __restrict__ colssq, const float* __restrict__ coldiff,
    const float* __restrict__ impre, const float* __restrict__ tip, const float* __restrict__ dmean,
    float* __restrict__ bstats, int* __restrict__ gmask, int* __restrict__ kpany)
{
  const int b = blockIdx.x, t = threadIdx.x;
  float fr = 0.f;
  for (int d = t; d < D_; d += 256) {
    float sq = colssq[b*D_+d], df = coldiff[b*D_+d];
    fr += (sq - df*df/(float)(L_-1)) / (float)(L_-2);
  }
  float imin = 3e38f, imax = -3e38f, tmin = 3e38f, tmax = -3e38f;
  double dsum = 0.0, dsq = 0.0;
  for (int i = t; i < L_; i += 256) {
    float ip = impre[b*L_+i]; imin = fminf(imin, ip); imax = fmaxf(imax, ip);
    float tv = tip[b*L_+i];   tmin = fminf(tmin, tv); tmax = fmaxf(tmax, tv);
    double dv = (double)dmean[b*L_+i]; dsum += dv; dsq += dv*dv;
    gmask[b*L_+i] = 0;
  }
  #pragma unroll
  for (int o = 32; o; o >>= 1) {
    fr += __shfl_down(fr, o);
    imin = fminf(imin, __shfl_down(imin, o));
    imax = fmaxf(imax, __shfl_down(imax, o));
    tmin = fminf(tmin, __shfl_down(tmin, o));
    tmax = fmaxf(tmax, __shfl_down(tmax, o));
    dsum += __shfl_down(dsum, o);
    dsq  += __shfl_down(dsq, o);
  }
  __shared__ float sf[5][4]; __shared__ double sd[2][4];
  int lane = t & 63, w = t >> 6;
  if (lane == 0) { sf[0][w]=fr; sf[1][w]=imin; sf[2][w]=imax; sf[3][w]=tmin; sf[4][w]=tmax; sd[0][w]=dsum; sd[1][w]=dsq; }
  __syncthreads();
  if (t == 0) {
    float FR   = sf[0][0]+sf[0][1]+sf[0][2]+sf[0][3];
    float IMIN = fminf(fminf(sf[1][0],sf[1][1]), fminf(sf[1][2],sf[1][3]));
    float IMAX = fmaxf(fmaxf(sf[2][0],sf[2][1]), fmaxf(sf[2][2],sf[2][3]));
    float TMIN = fminf(fminf(sf[3][0],sf[3][1]), fminf(sf[3][2],sf[3][3]));
    float TMAX = fmaxf(fmaxf(sf[4][0],sf[4][1]), fmaxf(sf[4][2],sf[4][3]));
    double DS = sd[0][0]+sd[0][1]+sd[0][2]+sd[0][3];
    double DQ = sd[1][0]+sd[1][1]+sd[1][2]+sd[1][3];
    double mean = DS/(double)L_;
    double var  = (DQ - DS*DS/(double)L_)/(double)(L_-1);
    bstats[b*8+0] = FR/(float)D_;          // freq
    bstats[b*8+1] = IMIN; bstats[b*8+2] = IMAX;
    bstats[b*8+3] = TMIN; bstats[b*8+4] = TMAX;
    bstats[b*8+5] = (float)(mean + 0.5*sqrt(var));   // thr
    kpany[b] = 0;
  }
}

// ---------------- finalize per-position (lw, fw, kp, impG) ----------------
__global__ __launch_bounds__(256) void k_finalize(const float* __restrict__ impre, const float* __restrict__ tip,
    const float* __restrict__ dmean, const float* __restrict__ maga, const float* __restrict__ d1a,
    const float* __restrict__ wvm, const float* __restrict__ bstats,
    int* __restrict__ lw, int* __restrict__ fw, int* __restrict__ kpA, int* __restrict__ kpany, float* __restrict__ impG)
{
  int idx = blockIdx.x*256 + threadIdx.x;   // b*L+i
  int b = idx / L_, i = idx % L_;
  float freq = bstats[b*8+0], imin = bstats[b*8+1], imax = bstats[b*8+2];
  float tmin = bstats[b*8+3], tmax = bstats[b*8+4], thr = bstats[b*8+5];
  float imp = (impre[idx]-imin)/(imax-imin+1e-6f);
  int lwv = (int)rintf(64.f*(0.5f+0.5f*imp));
  lw[idx] = min(max(lwv, 2), 128);
  float ti = (tip[idx]-tmin)/(tmax-tmin+1e-6f);
  int fwv = (int)rintf(32.f*(0.5f+0.5f*ti));
  fw[idx] = min(max(fwv, 1), 32);
  float dm = dmean[idx];
  bool kp;
  if (i == 0 || i == L_-1) kp = dm > thr;
  else kp = (dm > dmean[idx-1]) && (dm > dmean[idx+1]) && (dm > thr);
  kpA[idx] = kp ? 1 : 0;
  if (kp) atomicOr(&kpany[b], 1);
  float fs = (i == 0 || i == L_-1) ? 0.f : wvm[idx]/(freq+1e-6f);
  impG[idx] = 0.3f*maga[idx] + 0.4f*d1a[idx] + 0.3f*fs;
}

// ---------------- per-segment top-4 (stable, lower index wins ties) ----------------
__global__ __launch_bounds__(64) void k_topk(const float* __restrict__ impG, int* __restrict__ gmask) {
  int seg = blockIdx.x, b = blockIdx.y;
  int lane = threadIdx.x;                  // 64 lanes
  const float* base = impG + (size_t)b*L_ + seg*512;
  float vals[8];
  #pragma unroll
  for (int u = 0; u < 8; ++u) vals[u] = base[lane*8 + u];
  unsigned used = 0;
  for (int r = 0; r < 4; ++r) {
    float bv = -3e38f; int bi = 1 << 30;
    #pragma unroll
    for (int u = 0; u < 8; ++u) {
      if (!((used >> u) & 1)) { float v = vals[u]; if (v > bv) { bv = v; bi = lane*8 + u; } }
    }
    #pragma unroll
    for (int o = 32; o; o >>= 1) {
      float ov = __shfl_down(bv, o); int oi = __shfl_down(bi, o);
      if (ov > bv || (ov == bv && oi < bi)) { bv = ov; bi = oi; }
    }
    bi = __shfl(bi, 0);
    if (bi >> 3 == lane) used |= 1u << (bi & 7);
    if (lane == 0) gmask[(size_t)b*L_ + seg*512 + bi] = 1;
  }
}

// ---------------- fused GEMM: Y = f( pre(X) @ Wt^T + bias ) ----------------
// pre(X): optional layernorm (g,bb with rmean/rrstd) or optional elementwise mul
// act: 0 = none, 1 = sigmoid
__global__ __launch_bounds__(256) void k_gemm(const float* __restrict__ X, const float* __restrict__ Wt,
    const float* __restrict__ bias, const float* __restrict__ g, const float* __restrict__ bb,
    const float* __restrict__ rmean, const float* __restrict__ rrstd, const float* __restrict__ mul,
    float* __restrict__ Y, int act)
{
  __shared__ float4 AsV[64*17], BsV[64*17];
  float* As = (float*)AsV; float* Bs = (float*)BsV;
  const int tid = threadIdx.x, tx = tid & 15, ty = tid >> 4;
  const int bn = blockIdx.x, bm = blockIdx.y;
  float acc[4][4] = {};
  for (int kt = 0; kt < 8; ++kt) {
    const int k0 = kt*64;
    __syncthreads();
    #pragma unroll
    for (int p = 0; p < 4; ++p) {
      int idx = p*256 + tid, row = idx >> 4, fc = idx & 15;
      int m = bm*64 + row;
      float4 v = *(const float4*)(X + (size_t)m*D_ + k0 + fc*4);
      if (g) {
        float mm = rmean[m], rs = rrstd[m];
        int dd = k0 + fc*4;
        v.x = (v.x-mm)*rs*g[dd+0] + bb[dd+0];
        v.y = (v.y-mm)*rs*g[dd+1] + bb[dd+1];
        v.z = (v.z-mm)*rs*g[dd+2] + bb[dd+2];
        v.w = (v.w-mm)*rs*g[dd+3] + bb[dd+3];
      }
      if (mul) {
        float4 u = *(const float4*)(mul + (size_t)m*D_ + k0 + fc*4);
        v.x *= u.x; v.y *= u.y; v.z *= u.z; v.w *= u.w;
      }
      *(float4*)(As + row*68 + fc*4) = v;
      float4 wv = *(const float4*)(Wt + (size_t)(bn*64+row)*D_ + k0 + fc*4);
      *(float4*)(Bs + row*68 + fc*4) = wv;
    }
    __syncthreads();
    const float4* Af = (const float4*)As; const float4* Bf = (const float4*)Bs;
    #pragma unroll
    for (int kk = 0; kk < 16; ++kk) {
      float4 av[4], bv[4];
      #pragma unroll
      for (int u = 0; u < 4; ++u) av[u] = Af[(ty+16*u)*17 + kk];
      #pragma unroll
      for (int u = 0; u < 4; ++u) bv[u] = Bf[(tx+16*u)*17 + kk];
      #pragma unroll
      for (int ii = 0; ii < 4; ++ii)
        #pragma unroll
        for (int jj = 0; jj < 4; ++jj)
          acc[ii][jj] += dot4f(av[ii], bv[jj]);
    }
  }
  #pragma unroll
  for (int ii = 0; ii < 4; ++ii) {
    int m = bm*64 + ty + 16*ii;
    #pragma unroll
    for (int jj = 0; jj < 4; ++jj) {
      int n = bn*64 + tx + 16*jj;
      float v = acc[ii][jj] + bias[n];
      if (act == 1) v = 1.f/(1.f + expf(-v));
      Y[(size_t)m*D_ + n] = v;
    }
  }
}

// ---------------- flash attention with dynamic sparse mask ----------------
__global__ __launch_bounds__(256) void k_attn(const float* __restrict__ qb, const float* __restrict__ kb,
    const float* __restrict__ vb, const int* __restrict__ lw, const int* __restrict__ fw,
    const int* __restrict__ kpA, const int* __restrict__ gmask, const int* __restrict__ kpany,
    float* __restrict__ ctx)
{
  __shared__ float4 QsV[64*17], KsV[64*17], VtV[64*17];
  float* Qs = (float*)QsV; float* Ks = (float*)KsV; float* Vt = (float*)VtV;
  const int it = blockIdx.x, h = blockIdx.y, b = blockIdx.z;
  const int i0 = it*64;
  const int tid = threadIdx.x, tx = tid & 15, ty = tid >> 4;
  #pragma unroll
  for (int p = 0; p < 4; ++p) {
    int idx = p*256 + tid, row = idx >> 4, fc = idx & 15;
    float4 v = *(const float4*)(qb + ((size_t)(b*L_ + i0 + row))*D_ + h*HD_ + fc*4);
    v.x *= 0.125f; v.y *= 0.125f; v.z *= 0.125f; v.w *= 0.125f;   // 1/sqrt(HD)
    *(float4*)(Qs + row*68 + fc*4) = v;
  }
  int iw[4], lwv[4], fwv[4], kpi[4];
  #pragma unroll
  for (int a = 0; a < 4; ++a) {
    iw[a]  = i0 + ty + 16*a;
    lwv[a] = lw[b*L_ + iw[a]];
    fwv[a] = fw[b*L_ + iw[a]];
    kpi[a] = kpA[b*L_ + iw[a]];
  }
  const bool anyk = (kpany[b] != 0);
  float mrow[4], lrow[4], acc[4][4] = {};
  #pragma unroll
  for (int a = 0; a < 4; ++a) { mrow[a] = -3e38f; lrow[a] = 0.f; }

  for (int jt = 0; jt < 32; ++jt) {
    const int j0 = jt*64;
    __syncthreads();                       // previous PV readers done with Ks(Ps)/Vt
    #pragma unroll
    for (int p = 0; p < 4; ++p) {
      int idx = p*256 + tid, row = idx >> 4, fc = idx & 15;
      float4 kv = *(const float4*)(kb + ((size_t)(b*L_ + j0 + row))*D_ + h*HD_ + fc*4);
      *(float4*)(Ks + row*68 + fc*4) = kv;
      float4 vv = *(const float4*)(vb + ((size_t)(b*L_ + j0 + row))*D_ + h*HD_ + fc*4);
      Vt[(4*fc+0)*68 + row] = vv.x;       // transposed store: Vt[d][jc]
      Vt[(4*fc+1)*68 + row] = vv.y;
      Vt[(4*fc+2)*68 + row] = vv.z;
      Vt[(4*fc+3)*68 + row] = vv.w;
    }
    __syncthreads();
    float s[4][4] = {};
    {
      const float4* Qf = (const float4*)Qs; const float4* Kf = (const float4*)Ks;
      #pragma unroll
      for (int kk = 0; kk < 16; ++kk) {
        float4 av[4], bv[4];
        #pragma unroll
        for (int u = 0; u < 4; ++u) av[u] = Qf[(ty+16*u)*17 + kk];
        #pragma unroll
        for (int u = 0; u < 4; ++u) bv[u] = Kf[(tx+16*u)*17 + kk];
        #pragma unroll
        for (int ii = 0; ii < 4; ++ii)
          #pragma unroll
          for (int jj = 0; jj < 4; ++jj)
            s[ii][jj] += dot4f(av[ii], bv[jj]);
      }
    }
    __syncthreads();                       // done reading Ks; P will overwrite it
    int jg[4], kpj[4], gmj[4];
    #pragma unroll
    for (int jj = 0; jj < 4; ++jj) {
      jg[jj]  = j0 + tx + 16*jj;
      kpj[jj] = kpA[b*L_ + jg[jj]];
      gmj[jj] = gmask[b*L_ + jg[jj]];
    }
    #pragma unroll
    for (int a = 0; a < 4; ++a) {
      #pragma unroll
      for (int jj = 0; jj < 4; ++jj) {
        int iv = iw[a], j = jg[jj];
        bool allow = (j <= iv && j >= iv - lwv[a]) || (j > iv && j <= iv + fwv[a]);
        if (anyk) allow = allow || kpi[a] || kpj[jj];
        else      allow = allow || (j==0) || (j==511) || (j==1023) || (j==1535) || (j==2047);
        allow = allow || gmj[jj];
        if (!allow) s[a][jj] = -1e9f;
      }
    }
    float* Ps = Ks;                        // overlay P on K tile
    #pragma unroll
    for (int a = 0; a < 4; ++a) {
      float tm = fmaxf(fmaxf(s[a][0], s[a][1]), fmaxf(s[a][2], s[a][3]));
      tm = fmaxf(tm, __shfl_xor(tm, 1));
      tm = fmaxf(tm, __shfl_xor(tm, 2));
      tm = fmaxf(tm, __shfl_xor(tm, 4));
      tm = fmaxf(tm, __shfl_xor(tm, 8));
      float mn = fmaxf(mrow[a], tm);
      float rs = 0.f;
      #pragma unroll
      for (int jj = 0; jj < 4; ++jj) { float pv = expf(s[a][jj]-mn); s[a][jj] = pv; rs += pv; }
      rs += __shfl_xor(rs, 1); rs += __shfl_xor(rs, 2); rs += __shfl_xor(rs, 4); rs += __shfl_xor(rs, 8);
      float sc = expf(mrow[a] - mn);
      lrow[a] = lrow[a]*sc + rs;
      mrow[a] = mn;
      #pragma unroll
      for (int jj = 0; jj < 4; ++jj) { acc[a][jj] *= sc; Ps[(ty+16*a)*68 + tx + 16*jj] = s[a][jj]; }
    }
    __syncthreads();
    {
      const float4* Pf = (const float4*)Ps; const float4* Vf = (const float4*)Vt;
      #pragma unroll
      for (int kk = 0; kk < 16; ++kk) {
        float4 av[4], bv[4];
        #pragma unroll
        for (int u = 0; u < 4; ++u) av[u] = Pf[(ty+16*u)*17 + kk];
        #pragma unroll
        for (int u = 0; u < 4; ++u) bv[u] = Vf[(tx+16*u)*17 + kk];
        #pragma unroll
        for (int ii = 0; ii < 4; ++ii)
          #pragma unroll
          for (int jj = 0; jj < 4; ++jj)
            acc[ii][jj] += dot4f(av[ii], bv[jj]);
      }
    }
  }
  #pragma unroll
  for (int a = 0; a < 4; ++a) {
    float inv = 1.0f / lrow[a];
    #pragma unroll
    for (int jj = 0; jj < 4; ++jj) {
      ctx[((size_t)(b*L_ + iw[a]))*D_ + h*HD_ + tx + 16*jj] = acc[a][jj]*inv;
    }
  }
}

extern "C" void kernel_launch(void* const* d_in, const int* in_sizes, int n_in,
                              void* d_out, int out_size, void* d_ws, size_t ws_size,
                              hipStream_t stream) {
  (void)in_sizes; (void)n_in; (void)out_size; (void)ws_size;
  const float* x    = (const float*)d_in[0];
  const float* Wq   = (const float*)d_in[1];  const float* bq = (const float*)d_in[2];
  const float* Wk   = (const float*)d_in[3];  const float* bk = (const float*)d_in[4];
  const float* Wv   = (const float*)d_in[5];  const float* bv = (const float*)d_in[6];
  const float* Wo   = (const float*)d_in[7];  const float* bo = (const float*)d_in[8];
  const float* Wg   = (const float*)d_in[9];  const float* bg = (const float*)d_in[10];
  const float* lnqg = (const float*)d_in[11]; const float* lnqb = (const float*)d_in[12];
  const float* lnkg = (const float*)d_in[13]; const float* lnkb = (const float*)d_in[14];
  const float* lnvg = (const float*)d_in[15]; const float* lnvb = (const float*)d_in[16];
  float* out = (float*)d_out;

  float* Wbase = (float*)d_ws;
  size_t off = 0;
  auto alloc = [&](size_t n) { float* p = Wbase + off; off += n; return p; };
  const size_t BLD = (size_t)B_*L_*D_, DD = (size_t)D_*D_;
  float* qb    = alloc(BLD);
  float* kb    = alloc(BLD);
  float* vb    = alloc(BLD);
  float* gateb = alloc(BLD);
  float* ctxb  = alloc(BLD);
  float* Wqt = alloc(DD); float* Wkt = alloc(DD); float* Wvt = alloc(DD);
  float* Wgt = alloc(DD); float* Wot = alloc(DD);
  float* colmean = alloc(B_*D_); float* colssq = alloc(B_*D_); float* coldiff = alloc(B_*D_);
  float* pcs = alloc(32*B_*D_);  float* pcq = alloc(32*B_*D_);
  float* rowmean = alloc(B_*L_); float* rowrstd = alloc(B_*L_);
  float* impre = alloc(B_*L_);   float* tipA = alloc(B_*L_);   float* dmeanA = alloc(B_*L_);
  float* d1A = alloc(B_*L_);     float* magA = alloc(B_*L_);   float* wvmA = alloc(B_*L_);
  float* impG = alloc(B_*L_);
  float* bstats = alloc(32);
  int* lw     = (int*)alloc(B_*L_);
  int* fw     = (int*)alloc(B_*L_);
  int* kpA    = (int*)alloc(B_*L_);
  int* gmaskA = (int*)alloc(B_*L_);
  int* kpany  = (int*)alloc(16);

  TPtrs tp;
  tp.in[0] = Wq; tp.out[0] = Wqt;
  tp.in[1] = Wk; tp.out[1] = Wkt;
  tp.in[2] = Wv; tp.out[2] = Wvt;
  tp.in[3] = Wg; tp.out[3] = Wgt;
  tp.in[4] = Wo; tp.out[4] = Wot;
  k_transpose5<<<dim3(16,16,5), dim3(32,8), 0, stream>>>(tp);

  k_colstats_a<<<128, 256, 0, stream>>>(x, pcs, pcq);
  k_colstats_b<<<4, 256, 0, stream>>>(x, pcs, pcq, colmean, colssq, coldiff);
  k_rowstats<<<B_*L_, 256, 0, stream>>>(x, colmean, rowmean, rowrstd, impre, tipA, dmeanA, d1A, magA, wvmA);
  k_batchstats<<<B_, 256, 0, stream>>>(colssq, coldiff, impre, tipA, dmeanA, bstats, gmaskA, kpany);
  k_finalize<<<(B_*L_)/256, 256, 0, stream>>>(impre, tipA, dmeanA, magA, d1A, wvmA, bstats, lw, fw, kpA, kpany, impG);
  k_topk<<<dim3(4, B_), 64, 0, stream>>>(impG, gmaskA);

  k_gemm<<<dim3(8,64), 256, 0, stream>>>(x, Wqt, bq, lnqg, lnqb, rowmean, rowrstd, nullptr, qb, 0);
  k_gemm<<<dim3(8,64), 256, 0, stream>>>(x, Wkt, bk, lnkg, lnkb, rowmean, rowrstd, nullptr, kb, 0);
  k_gemm<<<dim3(8,64), 256, 0, stream>>>(x, Wvt, bv, lnvg, lnvb, rowmean, rowrstd, nullptr, vb, 0);
  k_gemm<<<dim3(8,64), 256, 0, stream>>>(x, Wgt, bg, nullptr, nullptr, nullptr, nullptr, nullptr, gateb, 1);

  k_attn<<<dim3(32, H_, B_), 256, 0, stream>>>(qb, kb, vb, lw, fw, kpA, gmaskA, kpany, ctxb);

  k_gemm<<<dim3(8,64), 256, 0, stream>>>(ctxb, Wot, bo, nullptr, nullptr, nullptr, nullptr, gateb, out, 0);
}

// Round 4
// 949.930 us; speedup vs baseline: 1.7637x; 1.7637x over previous
//
#include <hip/hip_runtime.h>
#include <hip/hip_bf16.h>
#include <cstdint>
#include <cstddef>

#define B_ 2
#define L_ 2048
#define D_ 512
#define H_ 8
#define HD_ 64

typedef __attribute__((ext_vector_type(8))) short bf16x8;
typedef __attribute__((ext_vector_type(4))) short s16x4;
typedef __attribute__((ext_vector_type(4))) float f32x4;

__device__ __forceinline__ float dot4f(float4 a, float4 b) {
  return a.x*b.x + a.y*b.y + a.z*b.z + a.w*b.w;
}

// RNE f32 -> bf16 (finite inputs only)
__device__ __forceinline__ short f2bf(float x) {
  unsigned u = __float_as_uint(x);
  unsigned r = (u + 0x7fffu + ((u >> 16) & 1u)) >> 16;
  return (short)r;
}
__device__ __forceinline__ float bf2f(short h) {
  return __uint_as_float(((unsigned)(unsigned short)h) << 16);
}

// ---------------- batched transpose of the five 512x512 weight matrices ----------------
struct TPtrs { const float* in[5]; float* out[5]; };

__global__ __launch_bounds__(256) void k_transpose5(TPtrs p) {
  __shared__ float tile[32][33];
  const float* in = p.in[blockIdx.z];
  float* out = p.out[blockIdx.z];
  int x = blockIdx.x*32 + threadIdx.x;
  int y = blockIdx.y*32 + threadIdx.y;
  #pragma unroll
  for (int j = 0; j < 32; j += 8) tile[threadIdx.y+j][threadIdx.x] = in[(size_t)(y+j)*D_ + x];
  __syncthreads();
  x = blockIdx.y*32 + threadIdx.x;
  y = blockIdx.x*32 + threadIdx.y;
  #pragma unroll
  for (int j = 0; j < 32; j += 8) out[(size_t)(y+j)*D_ + x] = tile[threadIdx.x][threadIdx.y+j];
}

// ---------------- column stats ----------------
__global__ __launch_bounds__(256) void k_colstats_a(const float* __restrict__ x, float* __restrict__ ps, float* __restrict__ pq) {
  int idx = blockIdx.x*256 + threadIdx.x;       // 32 * B * D = 32768
  int c   = idx >> 10;
  int rem = idx & 1023;
  int b = rem >> 9, d = rem & 511;
  const float* p = x + ((size_t)b*L_ + (size_t)c*64)*D_ + d;
  float s = 0.f, q = 0.f, prev;
  if (c == 0) {
    prev = p[0]; s = prev;
    for (int i = 1; i < 64; ++i) { float v = p[(size_t)i*D_]; float df = v - prev; q += df*df; s += v; prev = v; }
  } else {
    prev = *(p - D_);
    for (int i = 0; i < 64; ++i) { float v = p[(size_t)i*D_]; float df = v - prev; q += df*df; s += v; prev = v; }
  }
  ps[idx] = s; pq[idx] = q;
}
__global__ __launch_bounds__(256) void k_colstats_b(const float* __restrict__ x, const float* __restrict__ ps,
    const float* __restrict__ pq, float* __restrict__ colmean, float* __restrict__ colssq, float* __restrict__ coldiff) {
  int rem = blockIdx.x*256 + threadIdx.x;
  if (rem >= B_*D_) return;
  int b = rem >> 9, d = rem & 511;
  float s = 0.f, q = 0.f;
  for (int c = 0; c < 32; ++c) { s += ps[c*1024 + rem]; q += pq[c*1024 + rem]; }
  colmean[rem] = s / (float)L_;
  colssq[rem]  = q;
  coldiff[rem] = x[((size_t)b*L_ + (L_-1))*D_ + d] - x[((size_t)b*L_)*D_ + d];
}

// ---------------- per-row stats ----------------
__global__ __launch_bounds__(256) void k_rowstats(const float* __restrict__ x, const float* __restrict__ colmean,
    float* __restrict__ rowmean, float* __restrict__ rowrstd, float* __restrict__ impre, float* __restrict__ tip,
    float* __restrict__ dmean, float* __restrict__ d1a, float* __restrict__ maga, float* __restrict__ wvm)
{
  const int row = blockIdx.x;
  const int b = row / L_, i = row % L_;
  const int t = threadIdx.x;
  float sx=0, sxx=0, a1=0, a2=0, a3=0, a4=0, a5=0, tp=0, wv=0;
  const float* xb = x + (size_t)b*L_*D_;
  for (int d = t; d < D_; d += 256) {
    float r[8]; bool vl[8];
    #pragma unroll
    for (int k = 0; k < 8; ++k) {
      int p = i + k - 2;
      vl[k] = (p >= 0 && p < L_);
      r[k] = vl[k] ? xb[(size_t)p*D_ + d] : 0.f;
    }
    float xc = r[2];
    sx += xc; sxx += xc*xc;
    if (i+1 < L_) { a1 += fabsf(r[3]-xc); tp += fabsf(r[3] - colmean[b*D_+d]); }
    if (i+2 < L_) a2 += fabsf(r[4]-xc);
    if (i+3 < L_) a3 += fabsf(r[5]-xc);
    if (i+4 < L_) a4 += fabsf(r[6]-xc);
    if (i+5 < L_) a5 += fabsf(r[7]-xc);
    float wsum = 0.f; int n = 0;
    #pragma unroll
    for (int k = 0; k < 5; ++k) if (vl[k]) { wsum += r[k]; n++; }
    float wm = wsum / (float)n;
    float wq = 0.f;
    #pragma unroll
    for (int k = 0; k < 5; ++k) if (vl[k]) { float dv = r[k]-wm; wq += dv*dv; }
    wv += wq / (float)(n-1);
  }
  float vals[9] = {sx, sxx, a1, a2, a3, a4, a5, tp, wv};
  __shared__ float sm[9][4];
  int lane = t & 63, w = t >> 6;
  #pragma unroll
  for (int q = 0; q < 9; ++q) {
    float v = vals[q];
    #pragma unroll
    for (int o = 32; o; o >>= 1) v += __shfl_down(v, o);
    if (lane == 0) sm[q][w] = v;
  }
  __syncthreads();
  if (t == 0) {
    float S[9];
    #pragma unroll
    for (int q = 0; q < 9; ++q) S[q] = sm[q][0]+sm[q][1]+sm[q][2]+sm[q][3];
    float m  = S[0]/(float)D_;
    float var = S[1]/(float)D_ - m*m;
    rowmean[row] = m;
    rowrstd[row] = 1.0f/sqrtf(var + 1e-5f);
    maga[row] = sqrtf(S[1]);
    float d1 = S[2]/(float)D_;
    d1a[row] = d1;
    impre[row] = 0.5f*d1 + 0.3f*(S[3]/(float)D_)*0.5f + 0.2f*(S[5]/(float)D_)*0.25f;
    dmean[row] = 0.4f*d1 + 0.3f*(S[3]/(float)D_)*0.5f + 0.2f*(S[4]/(float)D_)*(1.f/3.f) + 0.1f*(S[6]/(float)D_)*0.2f;
    tip[row] = S[7]/(float)D_;
    wvm[row] = S[8]/(float)D_;
  }
}

// ---------------- per-batch stats ----------------
__global__ __launch_bounds__(256) void k_batchstats(const float* __restrict__ colssq, const float* __restrict__ coldiff,
    const float* __restrict__ impre, const float* __restrict__ tip, const float* __restrict__ dmean,
    float* __restrict__ bstats, int* __restrict__ kpany)
{
  const int b = blockIdx.x, t = threadIdx.x;
  float fr = 0.f;
  for (int d = t; d < D_; d += 256) {
    float sq = colssq[b*D_+d], df = coldiff[b*D_+d];
    fr += (sq - df*df/(float)(L_-1)) / (float)(L_-2);
  }
  float imin = 3e38f, imax = -3e38f, tmin = 3e38f, tmax = -3e38f;
  double dsum = 0.0, dsq = 0.0;
  for (int i = t; i < L_; i += 256) {
    float ip = impre[b*L_+i]; imin = fminf(imin, ip); imax = fmaxf(imax, ip);
    float tv = tip[b*L_+i];   tmin = fminf(tmin, tv); tmax = fmaxf(tmax, tv);
    double dv = (double)dmean[b*L_+i]; dsum += dv; dsq += dv*dv;
  }
  #pragma unroll
  for (int o = 32; o; o >>= 1) {
    fr += __shfl_down(fr, o);
    imin = fminf(imin, __shfl_down(imin, o));
    imax = fmaxf(imax, __shfl_down(imax, o));
    tmin = fminf(tmin, __shfl_down(tmin, o));
    tmax = fmaxf(tmax, __shfl_down(tmax, o));
    dsum += __shfl_down(dsum, o);
    dsq  += __shfl_down(dsq, o);
  }
  __shared__ float sf[5][4]; __shared__ double sd[2][4];
  int lane = t & 63, w = t >> 6;
  if (lane == 0) { sf[0][w]=fr; sf[1][w]=imin; sf[2][w]=imax; sf[3][w]=tmin; sf[4][w]=tmax; sd[0][w]=dsum; sd[1][w]=dsq; }
  __syncthreads();
  if (t == 0) {
    float FR   = sf[0][0]+sf[0][1]+sf[0][2]+sf[0][3];
    float IMIN = fminf(fminf(sf[1][0],sf[1][1]), fminf(sf[1][2],sf[1][3]));
    float IMAX = fmaxf(fmaxf(sf[2][0],sf[2][1]), fmaxf(sf[2][2],sf[2][3]));
    float TMIN = fminf(fminf(sf[3][0],sf[3][1]), fminf(sf[3][2],sf[3][3]));
    float TMAX = fmaxf(fmaxf(sf[4][0],sf[4][1]), fmaxf(sf[4][2],sf[4][3]));
    double DS = sd[0][0]+sd[0][1]+sd[0][2]+sd[0][3];
    double DQ = sd[1][0]+sd[1][1]+sd[1][2]+sd[1][3];
    double mean = DS/(double)L_;
    double var  = (DQ - DS*DS/(double)L_)/(double)(L_-1);
    bstats[b*8+0] = FR/(float)D_;
    bstats[b*8+1] = IMIN; bstats[b*8+2] = IMAX;
    bstats[b*8+3] = TMIN; bstats[b*8+4] = TMAX;
    bstats[b*8+5] = (float)(mean + 0.5*sqrt(var));
    kpany[b] = 0;
  }
}

// ---------------- finalize per-position ----------------
__global__ __launch_bounds__(256) void k_finalize(const float* __restrict__ impre, const float* __restrict__ tip,
    const float* __restrict__ dmean, const float* __restrict__ maga, const float* __restrict__ d1a,
    const float* __restrict__ wvm, const float* __restrict__ bstats,
    int* __restrict__ lw, int* __restrict__ fw, int* __restrict__ kpA, int* __restrict__ kpany, float* __restrict__ impG)
{
  int idx = blockIdx.x*256 + threadIdx.x;
  int b = idx / L_, i = idx % L_;
  float freq = bstats[b*8+0], imin = bstats[b*8+1], imax = bstats[b*8+2];
  float tmin = bstats[b*8+3], tmax = bstats[b*8+4], thr = bstats[b*8+5];
  float imp = (impre[idx]-imin)/(imax-imin+1e-6f);
  int lwv = (int)rintf(64.f*(0.5f+0.5f*imp));
  lw[idx] = min(max(lwv, 2), 128);
  float ti = (tip[idx]-tmin)/(tmax-tmin+1e-6f);
  int fwv = (int)rintf(32.f*(0.5f+0.5f*ti));
  fw[idx] = min(max(fwv, 1), 32);
  float dm = dmean[idx];
  bool kp;
  if (i == 0 || i == L_-1) kp = dm > thr;
  else kp = (dm > dmean[idx-1]) && (dm > dmean[idx+1]) && (dm > thr);
  kpA[idx] = kp ? 1 : 0;
  if (kp) atomicOr(&kpany[b], 1);
  float fs = (i == 0 || i == L_-1) ? 0.f : wvm[idx]/(freq+1e-6f);
  impG[idx] = 0.3f*maga[idx] + 0.4f*d1a[idx] + 0.3f*fs;
}

// ---------------- per-segment top-4 + jmask emit (kp bit0, global bit1) ----------------
__global__ __launch_bounds__(64) void k_topk(const float* __restrict__ impG, const int* __restrict__ kpA,
                                             unsigned char* __restrict__ jmask) {
  int seg = blockIdx.x, b = blockIdx.y;
  int lane = threadIdx.x;
  const float* base = impG + (size_t)b*L_ + seg*512;
  float vals[8];
  #pragma unroll
  for (int u = 0; u < 8; ++u) vals[u] = base[lane*8 + u];
  unsigned used = 0;
  for (int r = 0; r < 4; ++r) {
    float bv = -3e38f; int bi = 1 << 30;
    #pragma unroll
    for (int u = 0; u < 8; ++u) {
      if (!((used >> u) & 1)) { float v = vals[u]; if (v > bv) { bv = v; bi = lane*8 + u; } }
    }
    #pragma unroll
    for (int o = 32; o; o >>= 1) {
      float ov = __shfl_down(bv, o); int oi = __shfl_down(bi, o);
      if (ov > bv || (ov == bv && oi < bi)) { bv = ov; bi = oi; }
    }
    bi = __shfl(bi, 0);
    if (bi >> 3 == lane) used |= 1u << (bi & 7);
  }
  unsigned lo = 0, hi = 0;
  #pragma unroll
  for (int u = 0; u < 8; ++u) {
    unsigned f = (kpA[(size_t)b*L_ + seg*512 + lane*8 + u] ? 1u : 0u) | (((used >> u) & 1u) << 1);
    if (u < 4) lo |= f << (8*u); else hi |= f << (8*(u-4));
  }
  *(uint2*)(jmask + (size_t)b*L_ + seg*512 + lane*8) = make_uint2(lo, hi);
}

// ---------------- fused GEMM: Y = f( pre(X) @ Wt^T + bias ) ----------------
// mode 0: fp32 row-major; mode 1: bf16 hi/lo [bh][i][d] * oscale; mode 2: bf16 hi/lo [bh][d][i]
__global__ __launch_bounds__(256) void k_gemm(const float* __restrict__ X, const float* __restrict__ Wt,
    const float* __restrict__ bias, const float* __restrict__ g, const float* __restrict__ bb,
    const float* __restrict__ rmean, const float* __restrict__ rrstd, const float* __restrict__ mul,
    float* __restrict__ Yf, ushort* __restrict__ Yhi, ushort* __restrict__ Ylo,
    int mode, int act, float oscale)
{
  __shared__ float4 AsV[64*17], BsV[64*17];
  float* As = (float*)AsV; float* Bs = (float*)BsV;
  const int tid = threadIdx.x, tx = tid & 15, ty = tid >> 4;
  const int bn = blockIdx.x, bm = blockIdx.y;
  float acc[4][4] = {};
  for (int kt = 0; kt < 8; ++kt) {
    const int k0 = kt*64;
    __syncthreads();
    #pragma unroll
    for (int p = 0; p < 4; ++p) {
      int idx = p*256 + tid, row = idx >> 4, fc = idx & 15;
      int m = bm*64 + row;
      float4 v = *(const float4*)(X + (size_t)m*D_ + k0 + fc*4);
      if (g) {
        float mm = rmean[m], rs = rrstd[m];
        int dd = k0 + fc*4;
        v.x = (v.x-mm)*rs*g[dd+0] + bb[dd+0];
        v.y = (v.y-mm)*rs*g[dd+1] + bb[dd+1];
        v.z = (v.z-mm)*rs*g[dd+2] + bb[dd+2];
        v.w = (v.w-mm)*rs*g[dd+3] + bb[dd+3];
      }
      if (mul) {
        float4 u = *(const float4*)(mul + (size_t)m*D_ + k0 + fc*4);
        v.x *= u.x; v.y *= u.y; v.z *= u.z; v.w *= u.w;
      }
      *(float4*)(As + row*68 + fc*4) = v;
      float4 wv = *(const float4*)(Wt + (size_t)(bn*64+row)*D_ + k0 + fc*4);
      *(float4*)(Bs + row*68 + fc*4) = wv;
    }
    __syncthreads();
    const float4* Af = (const float4*)As; const float4* Bf = (const float4*)Bs;
    #pragma unroll
    for (int kk = 0; kk < 16; ++kk) {
      float4 av[4], bv[4];
      #pragma unroll
      for (int u = 0; u < 4; ++u) av[u] = Af[(ty+16*u)*17 + kk];
      #pragma unroll
      for (int u = 0; u < 4; ++u) bv[u] = Bf[(tx+16*u)*17 + kk];
      #pragma unroll
      for (int ii = 0; ii < 4; ++ii)
        #pragma unroll
        for (int jj = 0; jj < 4; ++jj)
          acc[ii][jj] += dot4f(av[ii], bv[jj]);
    }
  }
  #pragma unroll
  for (int ii = 0; ii < 4; ++ii) {
    int m = bm*64 + ty + 16*ii;
    #pragma unroll
    for (int jj = 0; jj < 4; ++jj) {
      int n = bn*64 + tx + 16*jj;
      float v = acc[ii][jj] + bias[n];
      if (act == 1) v = 1.f/(1.f + expf(-v));
      if (mode == 0) {
        Yf[(size_t)m*D_ + n] = v;
      } else {
        int b = m >> 11, i = m & 2047, h2 = n >> 6, d = n & 63;
        size_t idx = (mode == 1) ? (((size_t)(b*H_+h2)*L_ + i)*HD_ + d)
                                 : (((size_t)(b*H_+h2)*HD_ + d)*L_ + i);
        float vs = v * oscale;
        short hi = f2bf(vs);
        Yhi[idx] = (ushort)hi;
        Ylo[idx] = (ushort)f2bf(vs - bf2f(hi));
      }
    }
  }
}

// ---------------- MFMA flash attention (bf16x3 split precision) ----------------
// q/k hi+lo: bf16 [bh][i][d] (q pre-scaled 0.125); v hi+lo: bf16 [bh][d][j]
// Per wave: 16 Q rows; S^T = K x Q^T so each lane's 16 scores share row i = i0w + (lane&15).
__global__ __launch_bounds__(256) void k_attn(
    const ushort* __restrict__ qhi, const ushort* __restrict__ qlo,
    const ushort* __restrict__ khi, const ushort* __restrict__ klo,
    const ushort* __restrict__ vhi, const ushort* __restrict__ vlo,
    const int* __restrict__ lw, const int* __restrict__ fw, const int* __restrict__ kpA,
    const unsigned char* __restrict__ jmask, const int* __restrict__ kpany,
    float* __restrict__ ctx)
{
  const int it = blockIdx.x, h = blockIdx.y, b = blockIdx.z;
  const int bh = b*H_ + h;
  const int tid = threadIdx.x;
  const int w = tid >> 6, lane = tid & 63;
  const int l15 = lane & 15, l4 = lane >> 4;
  const int i0w = it*64 + w*16;
  const int ig = i0w + l15;                     // this lane's softmax row

  const size_t qoff = ((size_t)bh*L_ + ig)*HD_ + l4*8;
  bf16x8 qh0 = *(const bf16x8*)(qhi + qoff);
  bf16x8 qh1 = *(const bf16x8*)(qhi + qoff + 32);
  bf16x8 ql0 = *(const bf16x8*)(qlo + qoff);
  bf16x8 ql1 = *(const bf16x8*)(qlo + qoff + 32);

  const int lwv = lw[b*L_ + ig];
  const int fwv = fw[b*L_ + ig];
  const bool kpi = kpA[b*L_ + ig] != 0;
  const bool anyk = kpany[b] != 0;

  const size_t kbase = (size_t)bh*L_*HD_;
  const size_t vbase = (size_t)bh*HD_*L_;
  const unsigned char* jmb = jmask + (size_t)b*L_;

  f32x4 z4 = {0.f, 0.f, 0.f, 0.f};
  f32x4 o[4]; o[0]=z4; o[1]=z4; o[2]=z4; o[3]=z4;   // o[t2][r]: O[i_loc=4*l4+r][d=16*t2+l15]
  float mrow = -3e38f, lrow = 0.f;

  for (int jt = 0; jt < 32; ++jt) {
    const int j0 = jt*64;
    // ---- S^T = K x Q^T (bf16x3): s[t][r] = S[ig][j0 + 16t + 4*l4 + r] ----
    f32x4 s[4]; s[0]=z4; s[1]=z4; s[2]=z4; s[3]=z4;
    #pragma unroll
    for (int t = 0; t < 4; ++t) {
      const size_t koff = kbase + (size_t)(j0 + 16*t + l15)*HD_ + l4*8;
      bf16x8 kh0 = *(const bf16x8*)(khi + koff);
      bf16x8 kh1 = *(const bf16x8*)(khi + koff + 32);
      bf16x8 kl0 = *(const bf16x8*)(klo + koff);
      bf16x8 kl1 = *(const bf16x8*)(klo + koff + 32);
      s[t] = __builtin_amdgcn_mfma_f32_16x16x32_bf16(kh0, qh0, s[t], 0, 0, 0);
      s[t] = __builtin_amdgcn_mfma_f32_16x16x32_bf16(kh1, qh1, s[t], 0, 0, 0);
      s[t] = __builtin_amdgcn_mfma_f32_16x16x32_bf16(kh0, ql0, s[t], 0, 0, 0);
      s[t] = __builtin_amdgcn_mfma_f32_16x16x32_bf16(kh1, ql1, s[t], 0, 0, 0);
      s[t] = __builtin_amdgcn_mfma_f32_16x16x32_bf16(kl0, qh0, s[t], 0, 0, 0);
      s[t] = __builtin_amdgcn_mfma_f32_16x16x32_bf16(kl1, qh1, s[t], 0, 0, 0);
    }
    // ---- mask ----
    #pragma unroll
    for (int t = 0; t < 4; ++t) {
      const unsigned jm = *(const unsigned*)(jmb + j0 + 16*t + 4*l4);
      #pragma unroll
      for (int r = 0; r < 4; ++r) {
        int j = j0 + 16*t + 4*l4 + r;
        unsigned fl = jm >> (8*r);
        bool allow = (j <= ig) ? (j >= ig - lwv) : (j <= ig + fwv);
        allow = allow || ((fl & 2u) != 0u);
        if (anyk) allow = allow || kpi || ((fl & 1u) != 0u);
        else      allow = allow || (j==0) || (j==511) || (j==1023) || (j==1535) || (j==2047);
        if (!allow) s[t][r] = -1e9f;
      }
    }
    // ---- online softmax over row ig (partners: lanes ^16, ^32) ----
    float tm = fmaxf(
        fmaxf(fmaxf(fmaxf(s[0][0],s[0][1]), fmaxf(s[0][2],s[0][3])),
              fmaxf(fmaxf(s[1][0],s[1][1]), fmaxf(s[1][2],s[1][3]))),
        fmaxf(fmaxf(fmaxf(s[2][0],s[2][1]), fmaxf(s[2][2],s[2][3])),
              fmaxf(fmaxf(s[3][0],s[3][1]), fmaxf(s[3][2],s[3][3]))));
    tm = fmaxf(tm, __shfl_xor(tm, 16));
    tm = fmaxf(tm, __shfl_xor(tm, 32));
    const float mnew = fmaxf(mrow, tm);
    const float sc = __expf(mrow - mnew);
    float rs = 0.f;
    #pragma unroll
    for (int t = 0; t < 4; ++t) {
      #pragma unroll
      for (int r = 0; r < 4; ++r) { float p = __expf(s[t][r] - mnew); s[t][r] = p; rs += p; }
    }
    rs += __shfl_xor(rs, 16);
    rs += __shfl_xor(rs, 32);
    lrow = lrow*sc + rs;
    mrow = mnew;
    // ---- rescale O (scale for row 4*l4+r lives in lane 4*l4+r) ----
    #pragma unroll
    for (int r = 0; r < 4; ++r) {
      float scR = __shfl(sc, 4*l4 + r);
      o[0][r] *= scR; o[1][r] *= scR; o[2][r] *= scR; o[3][r] *= scR;
    }
    // ---- pack P hi/lo into A-frags: slot(l4,e) <-> j = 32c + 16*(e>>2) + 4*l4 + (e&3) ----
    bf16x8 ph0, ph1, pl0, pl1;
    #pragma unroll
    for (int e = 0; e < 8; ++e) {
      {
        float pv = s[e>>2][e&3];
        short hi = f2bf(pv);
        ph0[e] = hi; pl0[e] = f2bf(pv - bf2f(hi));
      }
      {
        float pv = s[2 + (e>>2)][e&3];
        short hi = f2bf(pv);
        ph1[e] = hi; pl1[e] = f2bf(pv - bf2f(hi));
      }
    }
    // ---- PV (bf16x3): o[t2] += P x V, V fragments use the same slot->j map ----
    #pragma unroll
    for (int t2 = 0; t2 < 4; ++t2) {
      const size_t voff = vbase + (size_t)(16*t2 + l15)*L_ + j0 + 4*l4;
      s16x4 a0 = *(const s16x4*)(vhi + voff);
      s16x4 a1 = *(const s16x4*)(vhi + voff + 16);
      s16x4 a2 = *(const s16x4*)(vhi + voff + 32);
      s16x4 a3 = *(const s16x4*)(vhi + voff + 48);
      bf16x8 vh0 = __builtin_shufflevector(a0, a1, 0,1,2,3,4,5,6,7);
      bf16x8 vh1 = __builtin_shufflevector(a2, a3, 0,1,2,3,4,5,6,7);
      s16x4 b0 = *(const s16x4*)(vlo + voff);
      s16x4 b1 = *(const s16x4*)(vlo + voff + 16);
      s16x4 b2 = *(const s16x4*)(vlo + voff + 32);
      s16x4 b3 = *(const s16x4*)(vlo + voff + 48);
      bf16x8 vl0 = __builtin_shufflevector(b0, b1, 0,1,2,3,4,5,6,7);
      bf16x8 vl1 = __builtin_shufflevector(b2, b3, 0,1,2,3,4,5,6,7);
      o[t2] = __builtin_amdgcn_mfma_f32_16x16x32_bf16(ph0, vh0, o[t2], 0, 0, 0);
      o[t2] = __builtin_amdgcn_mfma_f32_16x16x32_bf16(ph1, vh1, o[t2], 0, 0, 0);
      o[t2] = __builtin_amdgcn_mfma_f32_16x16x32_bf16(ph0, vl0, o[t2], 0, 0, 0);
      o[t2] = __builtin_amdgcn_mfma_f32_16x16x32_bf16(ph1, vl1, o[t2], 0, 0, 0);
      o[t2] = __builtin_amdgcn_mfma_f32_16x16x32_bf16(pl0, vh0, o[t2], 0, 0, 0);
      o[t2] = __builtin_amdgcn_mfma_f32_16x16x32_bf16(pl1, vh1, o[t2], 0, 0, 0);
    }
  }
  // ---- normalize + write ctx (fp32) ----
  #pragma unroll
  for (int r = 0; r < 4; ++r) {
    float linv = 1.0f / __shfl(lrow, 4*l4 + r);
    int iw_ = i0w + 4*l4 + r;
    float* cp = ctx + ((size_t)b*L_ + iw_)*D_ + h*HD_ + l15;
    #pragma unroll
    for (int t2 = 0; t2 < 4; ++t2) cp[16*t2] = o[t2][r] * linv;
  }
}

extern "C" void kernel_launch(void* const* d_in, const int* in_sizes, int n_in,
                              void* d_out, int out_size, void* d_ws, size_t ws_size,
                              hipStream_t stream) {
  (void)in_sizes; (void)n_in; (void)out_size; (void)ws_size;
  const float* x    = (const float*)d_in[0];
  const float* Wq   = (const float*)d_in[1];  const float* bq = (const float*)d_in[2];
  const float* Wk   = (const float*)d_in[3];  const float* bk = (const float*)d_in[4];
  const float* Wv   = (const float*)d_in[5];  const float* bv = (const float*)d_in[6];
  const float* Wo   = (const float*)d_in[7];  const float* bo = (const float*)d_in[8];
  const float* Wg   = (const float*)d_in[9];  const float* bg = (const float*)d_in[10];
  const float* lnqg = (const float*)d_in[11]; const float* lnqb = (const float*)d_in[12];
  const float* lnkg = (const float*)d_in[13]; const float* lnkb = (const float*)d_in[14];
  const float* lnvg = (const float*)d_in[15]; const float* lnvb = (const float*)d_in[16];
  float* out = (float*)d_out;

  float* Wbase = (float*)d_ws;
  size_t off = 0;
  auto alloc = [&](size_t n) { float* p = Wbase + off; off += n; return p; };
  const size_t BLD = (size_t)B_*L_*D_, DD = (size_t)D_*D_;
  float* gateb = alloc(BLD);
  float* ctxb  = alloc(BLD);
  ushort* qhi = (ushort*)alloc(BLD/2);  ushort* qlo = (ushort*)alloc(BLD/2);
  ushort* khi = (ushort*)alloc(BLD/2);  ushort* klo = (ushort*)alloc(BLD/2);
  ushort* vhi = (ushort*)alloc(BLD/2);  ushort* vlo = (ushort*)alloc(BLD/2);
  float* Wqt = alloc(DD); float* Wkt = alloc(DD); float* Wvt = alloc(DD);
  float* Wgt = alloc(DD); float* Wot = alloc(DD);
  float* colmean = alloc(B_*D_); float* colssq = alloc(B_*D_); float* coldiff = alloc(B_*D_);
  float* pcs = alloc(32*B_*D_);  float* pcq = alloc(32*B_*D_);
  float* rowmean = alloc(B_*L_); float* rowrstd = alloc(B_*L_);
  float* impre = alloc(B_*L_);   float* tipA = alloc(B_*L_);   float* dmeanA = alloc(B_*L_);
  float* d1A = alloc(B_*L_);     float* magA = alloc(B_*L_);   float* wvmA = alloc(B_*L_);
  float* impG = alloc(B_*L_);
  float* bstats = alloc(32);
  int* lw     = (int*)alloc(B_*L_);
  int* fw     = (int*)alloc(B_*L_);
  int* kpA    = (int*)alloc(B_*L_);
  int* kpany  = (int*)alloc(16);
  unsigned char* jmaskA = (unsigned char*)alloc(B_*L_/4);

  TPtrs tp;
  tp.in[0] = Wq; tp.out[0] = Wqt;
  tp.in[1] = Wk; tp.out[1] = Wkt;
  tp.in[2] = Wv; tp.out[2] = Wvt;
  tp.in[3] = Wg; tp.out[3] = Wgt;
  tp.in[4] = Wo; tp.out[4] = Wot;
  k_transpose5<<<dim3(16,16,5), dim3(32,8), 0, stream>>>(tp);

  k_colstats_a<<<128, 256, 0, stream>>>(x, pcs, pcq);
  k_colstats_b<<<4, 256, 0, stream>>>(x, pcs, pcq, colmean, colssq, coldiff);
  k_rowstats<<<B_*L_, 256, 0, stream>>>(x, colmean, rowmean, rowrstd, impre, tipA, dmeanA, d1A, magA, wvmA);
  k_batchstats<<<B_, 256, 0, stream>>>(colssq, coldiff, impre, tipA, dmeanA, bstats, kpany);
  k_finalize<<<(B_*L_)/256, 256, 0, stream>>>(impre, tipA, dmeanA, magA, d1A, wvmA, bstats, lw, fw, kpA, kpany, impG);
  k_topk<<<dim3(4, B_), 64, 0, stream>>>(impG, kpA, jmaskA);

  // q scaled by 1/sqrt(HD) at bf16-store time
  k_gemm<<<dim3(8,64), 256, 0, stream>>>(x, Wqt, bq, lnqg, lnqb, rowmean, rowrstd, nullptr, nullptr, qhi, qlo, 1, 0, 0.125f);
  k_gemm<<<dim3(8,64), 256, 0, stream>>>(x, Wkt, bk, lnkg, lnkb, rowmean, rowrstd, nullptr, nullptr, khi, klo, 1, 0, 1.0f);
  k_gemm<<<dim3(8,64), 256, 0, stream>>>(x, Wvt, bv, lnvg, lnvb, rowmean, rowrstd, nullptr, nullptr, vhi, vlo, 2, 0, 1.0f);
  k_gemm<<<dim3(8,64), 256, 0, stream>>>(x, Wgt, bg, nullptr, nullptr, nullptr, nullptr, nullptr, gateb, nullptr, nullptr, 0, 1, 1.0f);

  k_attn<<<dim3(32, H_, B_), 256, 0, stream>>>(qhi, qlo, khi, klo, vhi, vlo, lw, fw, kpA, jmaskA, kpany, ctxb);

  k_gemm<<<dim3(8,64), 256, 0, stream>>>(ctxb, Wot, bo, nullptr, nullptr, nullptr, nullptr, gateb, out, nullptr, nullptr, 0, 0, 1.0f);
}

// Round 10
// 763.479 us; speedup vs baseline: 2.1944x; 1.2442x over previous
//
#include <hip/hip_runtime.h>
#include <hip/hip_bf16.h>
#include <cstdint>
#include <cstddef>

#define B_ 2
#define L_ 2048
#define D_ 512
#define H_ 8
#define HD_ 64

typedef __attribute__((ext_vector_type(8))) short bf16x8;
typedef __attribute__((ext_vector_type(4))) short s16x4;
typedef __attribute__((ext_vector_type(4))) float f32x4;

// RNE f32 -> bf16 (finite inputs only)
__device__ __forceinline__ short f2bf(float x) {
  unsigned u = __float_as_uint(x);
  unsigned r = (u + 0x7fffu + ((u >> 16) & 1u)) >> 16;
  return (short)r;
}
__device__ __forceinline__ float bf2f(short h) {
  return __uint_as_float(((unsigned)(unsigned short)h) << 16);
}

// ---------------- transpose + scale + hi/lo split of the five 512x512 weights ----------------
// emits Bt[n][k] = W[k][n] * (g ? g[k] : 1) as bf16 hi/lo
struct TPtrs { const float* in[5]; const float* gv[5]; ushort* oh[5]; ushort* ol[5]; };

__global__ __launch_bounds__(256) void k_transpose5(TPtrs p) {
  __shared__ float tile[32][33];
  const float* in = p.in[blockIdx.z];
  const float* gv = p.gv[blockIdx.z];
  ushort* oh = p.oh[blockIdx.z];
  ushort* ol = p.ol[blockIdx.z];
  int x = blockIdx.x*32 + threadIdx.x;
  int y = blockIdx.y*32 + threadIdx.y;
  #pragma unroll
  for (int j = 0; j < 32; j += 8) tile[threadIdx.y+j][threadIdx.x] = in[(size_t)(y+j)*D_ + x];
  __syncthreads();
  int x2 = blockIdx.y*32 + threadIdx.x;      // k
  int y2 = blockIdx.x*32 + threadIdx.y;      // n
  float s = gv ? gv[x2] : 1.0f;
  #pragma unroll
  for (int j = 0; j < 32; j += 8) {
    float v = tile[threadIdx.x][threadIdx.y+j] * s;
    short hi = f2bf(v);
    oh[(size_t)(y2+j)*D_ + x2] = (ushort)hi;
    ol[(size_t)(y2+j)*D_ + x2] = (ushort)f2bf(v - bf2f(hi));
  }
}

// ---------------- bias fold: out[n] = bias[n] + sum_k lnb[k] * W[k][n] ----------------
__global__ __launch_bounds__(256) void k_biasfold(const float* __restrict__ W, const float* __restrict__ lnb,
                                                  const float* __restrict__ bias, float* __restrict__ outb) {
  int n = blockIdx.x*256 + threadIdx.x;
  float s = bias[n];
  for (int k = 0; k < D_; ++k) s += lnb[k] * W[(size_t)k*D_ + n];
  outb[n] = s;
}

// ---------------- column stats ----------------
__global__ __launch_bounds__(256) void k_colstats_a(const float* __restrict__ x, float* __restrict__ ps, float* __restrict__ pq) {
  int idx = blockIdx.x*256 + threadIdx.x;       // 32 * B * D = 32768
  int c   = idx >> 10;
  int rem = idx & 1023;
  int b = rem >> 9, d = rem & 511;
  const float* p = x + ((size_t)b*L_ + (size_t)c*64)*D_ + d;
  float s = 0.f, q = 0.f, prev;
  if (c == 0) {
    prev = p[0]; s = prev;
    for (int i = 1; i < 64; ++i) { float v = p[(size_t)i*D_]; float df = v - prev; q += df*df; s += v; prev = v; }
  } else {
    prev = *(p - D_);
    for (int i = 0; i < 64; ++i) { float v = p[(size_t)i*D_]; float df = v - prev; q += df*df; s += v; prev = v; }
  }
  ps[idx] = s; pq[idx] = q;
}
__global__ __launch_bounds__(256) void k_colstats_b(const float* __restrict__ x, const float* __restrict__ ps,
    const float* __restrict__ pq, float* __restrict__ colmean, float* __restrict__ colssq, float* __restrict__ coldiff) {
  int rem = blockIdx.x*256 + threadIdx.x;
  if (rem >= B_*D_) return;
  int b = rem >> 9, d = rem & 511;
  float s = 0.f, q = 0.f;
  for (int c = 0; c < 32; ++c) { s += ps[c*1024 + rem]; q += pq[c*1024 + rem]; }
  colmean[rem] = s / (float)L_;
  colssq[rem]  = q;
  coldiff[rem] = x[((size_t)b*L_ + (L_-1))*D_ + d] - x[((size_t)b*L_)*D_ + d];
}

// ---------------- per-row stats ----------------
__global__ __launch_bounds__(256) void k_rowstats(const float* __restrict__ x, const float* __restrict__ colmean,
    float* __restrict__ rowmean, float* __restrict__ rowrstd, float* __restrict__ impre, float* __restrict__ tip,
    float* __restrict__ dmean, float* __restrict__ d1a, float* __restrict__ maga, float* __restrict__ wvm)
{
  const int row = blockIdx.x;
  const int b = row / L_, i = row % L_;
  const int t = threadIdx.x;
  float sx=0, sxx=0, a1=0, a2=0, a3=0, a4=0, a5=0, tp=0, wv=0;
  const float* xb = x + (size_t)b*L_*D_;
  for (int d = t; d < D_; d += 256) {
    float r[8]; bool vl[8];
    #pragma unroll
    for (int k = 0; k < 8; ++k) {
      int p = i + k - 2;
      vl[k] = (p >= 0 && p < L_);
      r[k] = vl[k] ? xb[(size_t)p*D_ + d] : 0.f;
    }
    float xc = r[2];
    sx += xc; sxx += xc*xc;
    if (i+1 < L_) { a1 += fabsf(r[3]-xc); tp += fabsf(r[3] - colmean[b*D_+d]); }
    if (i+2 < L_) a2 += fabsf(r[4]-xc);
    if (i+3 < L_) a3 += fabsf(r[5]-xc);
    if (i+4 < L_) a4 += fabsf(r[6]-xc);
    if (i+5 < L_) a5 += fabsf(r[7]-xc);
    float wsum = 0.f; int n = 0;
    #pragma unroll
    for (int k = 0; k < 5; ++k) if (vl[k]) { wsum += r[k]; n++; }
    float wm = wsum / (float)n;
    float wq = 0.f;
    #pragma unroll
    for (int k = 0; k < 5; ++k) if (vl[k]) { float dv = r[k]-wm; wq += dv*dv; }
    wv += wq / (float)(n-1);
  }
  float vals[9] = {sx, sxx, a1, a2, a3, a4, a5, tp, wv};
  __shared__ float sm[9][4];
  int lane = t & 63, w = t >> 6;
  #pragma unroll
  for (int q = 0; q < 9; ++q) {
    float v = vals[q];
    #pragma unroll
    for (int o = 32; o; o >>= 1) v += __shfl_down(v, o);
    if (lane == 0) sm[q][w] = v;
  }
  __syncthreads();
  if (t == 0) {
    float S[9];
    #pragma unroll
    for (int q = 0; q < 9; ++q) S[q] = sm[q][0]+sm[q][1]+sm[q][2]+sm[q][3];
    float m  = S[0]/(float)D_;
    float var = S[1]/(float)D_ - m*m;
    rowmean[row] = m;
    rowrstd[row] = 1.0f/sqrtf(var + 1e-5f);
    maga[row] = sqrtf(S[1]);
    float d1 = S[2]/(float)D_;
    d1a[row] = d1;
    impre[row] = 0.5f*d1 + 0.3f*(S[3]/(float)D_)*0.5f + 0.2f*(S[5]/(float)D_)*0.25f;
    dmean[row] = 0.4f*d1 + 0.3f*(S[3]/(float)D_)*0.5f + 0.2f*(S[4]/(float)D_)*(1.f/3.f) + 0.1f*(S[6]/(float)D_)*0.2f;
    tip[row] = S[7]/(float)D_;
    wvm[row] = S[8]/(float)D_;
  }
}

// ---------------- per-batch stats ----------------
__global__ __launch_bounds__(256) void k_batchstats(const float* __restrict__ colssq, const float* __restrict__ coldiff,
    const float* __restrict__ impre, const float* __restrict__ tip, const float* __restrict__ dmean,
    float* __restrict__ bstats, int* __restrict__ kpany)
{
  const int b = blockIdx.x, t = threadIdx.x;
  float fr = 0.f;
  for (int d = t; d < D_; d += 256) {
    float sq = colssq[b*D_+d], df = coldiff[b*D_+d];
    fr += (sq - df*df/(float)(L_-1)) / (float)(L_-2);
  }
  float imin = 3e38f, imax = -3e38f, tmin = 3e38f, tmax = -3e38f;
  double dsum = 0.0, dsq = 0.0;
  for (int i = t; i < L_; i += 256) {
    float ip = impre[b*L_+i]; imin = fminf(imin, ip); imax = fmaxf(imax, ip);
    float tv = tip[b*L_+i];   tmin = fminf(tmin, tv); tmax = fmaxf(tmax, tv);
    double dv = (double)dmean[b*L_+i]; dsum += dv; dsq += dv*dv;
  }
  #pragma unroll
  for (int o = 32; o; o >>= 1) {
    fr += __shfl_down(fr, o);
    imin = fminf(imin, __shfl_down(imin, o));
    imax = fmaxf(imax, __shfl_down(imax, o));
    tmin = fminf(tmin, __shfl_down(tmin, o));
    tmax = fmaxf(tmax, __shfl_down(tmax, o));
    dsum += __shfl_down(dsum, o);
    dsq  += __shfl_down(dsq, o);
  }
  __shared__ float sf[5][4]; __shared__ double sd[2][4];
  int lane = t & 63, w = t >> 6;
  if (lane == 0) { sf[0][w]=fr; sf[1][w]=imin; sf[2][w]=imax; sf[3][w]=tmin; sf[4][w]=tmax; sd[0][w]=dsum; sd[1][w]=dsq; }
  __syncthreads();
  if (t == 0) {
    float FR   = sf[0][0]+sf[0][1]+sf[0][2]+sf[0][3];
    float IMIN = fminf(fminf(sf[1][0],sf[1][1]), fminf(sf[1][2],sf[1][3]));
    float IMAX = fmaxf(fmaxf(sf[2][0],sf[2][1]), fmaxf(sf[2][2],sf[2][3]));
    float TMIN = fminf(fminf(sf[3][0],sf[3][1]), fminf(sf[3][2],sf[3][3]));
    float TMAX = fmaxf(fmaxf(sf[4][0],sf[4][1]), fmaxf(sf[4][2],sf[4][3]));
    double DS = sd[0][0]+sd[0][1]+sd[0][2]+sd[0][3];
    double DQ = sd[1][0]+sd[1][1]+sd[1][2]+sd[1][3];
    double mean = DS/(double)L_;
    double var  = (DQ - DS*DS/(double)L_)/(double)(L_-1);
    bstats[b*8+0] = FR/(float)D_;
    bstats[b*8+1] = IMIN; bstats[b*8+2] = IMAX;
    bstats[b*8+3] = TMIN; bstats[b*8+4] = TMAX;
    bstats[b*8+5] = (float)(mean + 0.5*sqrt(var));
    kpany[b] = 0;
  }
}

// ---------------- finalize per-position ----------------
__global__ __launch_bounds__(256) void k_finalize(const float* __restrict__ impre, const float* __restrict__ tip,
    const float* __restrict__ dmean, const float* __restrict__ maga, const float* __restrict__ d1a,
    const float* __restrict__ wvm, const float* __restrict__ bstats,
    int* __restrict__ lw, int* __restrict__ fw, int* __restrict__ kpA, int* __restrict__ kpany, float* __restrict__ impG)
{
  int idx = blockIdx.x*256 + threadIdx.x;
  int b = idx / L_, i = idx % L_;
  float freq = bstats[b*8+0], imin = bstats[b*8+1], imax = bstats[b*8+2];
  float tmin = bstats[b*8+3], tmax = bstats[b*8+4], thr = bstats[b*8+5];
  float imp = (impre[idx]-imin)/(imax-imin+1e-6f);
  int lwv = (int)rintf(64.f*(0.5f+0.5f*imp));
  lw[idx] = min(max(lwv, 2), 128);
  float ti = (tip[idx]-tmin)/(tmax-tmin+1e-6f);
  int fwv = (int)rintf(32.f*(0.5f+0.5f*ti));
  fw[idx] = min(max(fwv, 1), 32);
  float dm = dmean[idx];
  bool kp;
  if (i == 0 || i == L_-1) kp = dm > thr;
  else kp = (dm > dmean[idx-1]) && (dm > dmean[idx+1]) && (dm > thr);
  kpA[idx] = kp ? 1 : 0;
  if (kp) atomicOr(&kpany[b], 1);
  float fs = (i == 0 || i == L_-1) ? 0.f : wvm[idx]/(freq+1e-6f);
  impG[idx] = 0.3f*maga[idx] + 0.4f*d1a[idx] + 0.3f*fs;
}

// ---------------- per-segment top-4 + jmask emit (kp bit0, global bit1) ----------------
__global__ __launch_bounds__(64) void k_topk(const float* __restrict__ impG, const int* __restrict__ kpA,
                                             unsigned char* __restrict__ jmask) {
  int seg = blockIdx.x, b = blockIdx.y;
  int lane = threadIdx.x;
  const float* base = impG + (size_t)b*L_ + seg*512;
  float vals[8];
  #pragma unroll
  for (int u = 0; u < 8; ++u) vals[u] = base[lane*8 + u];
  unsigned used = 0;
  for (int r = 0; r < 4; ++r) {
    float bv = -3e38f; int bi = 1 << 30;
    #pragma unroll
    for (int u = 0; u < 8; ++u) {
      if (!((used >> u) & 1)) { float v = vals[u]; if (v > bv) { bv = v; bi = lane*8 + u; } }
    }
    #pragma unroll
    for (int o = 32; o; o >>= 1) {
      float ov = __shfl_down(bv, o); int oi = __shfl_down(bi, o);
      if (ov > bv || (ov == bv && oi < bi)) { bv = ov; bi = oi; }
    }
    bi = __shfl(bi, 0);
    if (bi >> 3 == lane) used |= 1u << (bi & 7);
  }
  unsigned lo = 0, hi = 0;
  #pragma unroll
  for (int u = 0; u < 8; ++u) {
    unsigned f = (kpA[(size_t)b*L_ + seg*512 + lane*8 + u] ? 1u : 0u) | (((used >> u) & 1u) << 1);
    if (u < 4) lo |= f << (8*u); else hi |= f << (8*(u-4));
  }
  *(uint2*)(jmask + (size_t)b*L_ + seg*512 + lane*8) = make_uint2(lo, hi);
}

// ---------------- MFMA GEMM (bf16x3): C = A @ Bt^T + bias, A optionally LN'd fp32 ----------------
// A-source: Af fp32 [m][k] (rm/rs optional layernorm core) OR Ah/Al bf16 hi/lo [m][k]
// Bt hi/lo [n][k]. Wave tile 16m x 32n; block 256 = 4 waves (2m x 2n); grid (128, 8).
// mode 0: fp32 out; 1: sigmoid fp32; 2: q hi/lo [bh][i][d] *oscale; 3: k hi/lo [bh][i][d]; 4: v hi/lo [bh][d][i]
__global__ __launch_bounds__(256) void k_gemm_mfma(
    const float* __restrict__ Af, const ushort* __restrict__ Ah, const ushort* __restrict__ Al,
    const float* __restrict__ rm, const float* __restrict__ rs,
    const ushort* __restrict__ Bh, const ushort* __restrict__ Bl, const float* __restrict__ bias,
    float* __restrict__ Yf, ushort* __restrict__ Yhi, ushort* __restrict__ Ylo,
    int mode, float oscale)
{
  const int tid = threadIdx.x;
  const int w = tid >> 6, lane = tid & 63;
  const int l15 = lane & 15, l4 = lane >> 4;
  const int wm = w & 1, wn = w >> 1;
  const int m0 = blockIdx.x*32 + wm*16;
  const int n0 = blockIdx.y*64 + wn*32;

  float mm = 0.f, rsv = 1.f;
  if (Af && rm) { mm = rm[m0 + l15]; rsv = rs[m0 + l15]; }

  f32x4 z4 = {0.f,0.f,0.f,0.f};
  f32x4 acc[2]; acc[0] = z4; acc[1] = z4;

  for (int kc = 0; kc < 16; ++kc) {
    const int k0 = kc*32;
    bf16x8 xh, xl;
    if (Af) {
      const float* ap = Af + (size_t)(m0 + l15)*D_ + k0 + l4*8;
      float4 a0 = *(const float4*)ap;
      float4 a1 = *(const float4*)(ap + 4);
      float av[8] = {a0.x,a0.y,a0.z,a0.w,a1.x,a1.y,a1.z,a1.w};
      #pragma unroll
      for (int e = 0; e < 8; ++e) {
        float v = (av[e] - mm) * rsv;
        short hi = f2bf(v);
        xh[e] = hi; xl[e] = f2bf(v - bf2f(hi));
      }
    } else {
      const size_t ao = (size_t)(m0 + l15)*D_ + k0 + l4*8;
      xh = *(const bf16x8*)(Ah + ao);
      xl = *(const bf16x8*)(Al + ao);
    }
    #pragma unroll
    for (int t2 = 0; t2 < 2; ++t2) {
      const size_t bo = (size_t)(n0 + 16*t2 + l15)*D_ + k0 + l4*8;
      bf16x8 yh = *(const bf16x8*)(Bh + bo);
      bf16x8 yl = *(const bf16x8*)(Bl + bo);
      acc[t2] = __builtin_amdgcn_mfma_f32_16x16x32_bf16(xl, yh, acc[t2], 0, 0, 0);
      acc[t2] = __builtin_amdgcn_mfma_f32_16x16x32_bf16(xh, yl, acc[t2], 0, 0, 0);
      acc[t2] = __builtin_amdgcn_mfma_f32_16x16x32_bf16(xh, yh, acc[t2], 0, 0, 0);
    }
  }
  #pragma unroll
  for (int t2 = 0; t2 < 2; ++t2) {
    const int n = n0 + 16*t2 + l15;
    const float bs = bias[n];
    #pragma unroll
    for (int r = 0; r < 4; ++r) {
      const int m = m0 + 4*l4 + r;
      float v = acc[t2][r] + bs;
      if (mode == 0) {
        Yf[(size_t)m*D_ + n] = v;
      } else if (mode == 1) {
        Yf[(size_t)m*D_ + n] = 1.f/(1.f + expf(-v));
      } else {
        const int b = m >> 11, i = m & 2047, h2 = n >> 6, d = n & 63;
        const size_t idx = (mode == 4) ? (((size_t)(b*H_+h2)*HD_ + d)*L_ + i)
                                       : (((size_t)(b*H_+h2)*L_ + i)*HD_ + d);
        float vs = v * oscale;
        short hi = f2bf(vs);
        Yhi[idx] = (ushort)hi;
        Ylo[idx] = (ushort)f2bf(vs - bf2f(hi));
      }
    }
  }
}

// ---------------- MFMA flash attention, 4-way j-split, in-block merge ----------------
// q/k hi+lo: bf16 [bh][i][d] (q pre-scaled 0.125); v hi+lo: bf16 [bh][d][j]
// Block: 512 thr = 8 waves = 2 q-subtiles (16 rows) x 4 j-splits (8 tiles each). Grid (64, H, B).
// Epilogue: flash-decoding merge in LDS, multiply by gate, emit ctx*gate as bf16 hi/lo [m][k].
__global__ __launch_bounds__(512) void k_attn(
    const ushort* __restrict__ qhi, const ushort* __restrict__ qlo,
    const ushort* __restrict__ khi, const ushort* __restrict__ klo,
    const ushort* __restrict__ vhi, const ushort* __restrict__ vlo,
    const int* __restrict__ lw, const int* __restrict__ fw, const int* __restrict__ kpA,
    const unsigned char* __restrict__ jmask, const int* __restrict__ kpany,
    const float* __restrict__ gateb, ushort* __restrict__ cgh, ushort* __restrict__ cgl)
{
  __shared__ float lds_o[4][32][68];
  __shared__ float2 lds_ml[4][32];

  const int it = blockIdx.x, h = blockIdx.y, b = blockIdx.z;
  const int bh = b*H_ + h;
  const int tid = threadIdx.x;
  const int w = tid >> 6, lane = tid & 63;
  const int l15 = lane & 15, l4 = lane >> 4;
  const int wq = w & 1, sp = w >> 1;
  const int i0w = it*32 + wq*16;
  const int ig = i0w + l15;                     // this lane's softmax row

  const size_t qoff = ((size_t)bh*L_ + ig)*HD_ + l4*8;
  bf16x8 qh0 = *(const bf16x8*)(qhi + qoff);
  bf16x8 qh1 = *(const bf16x8*)(qhi + qoff + 32);
  bf16x8 ql0 = *(const bf16x8*)(qlo + qoff);
  bf16x8 ql1 = *(const bf16x8*)(qlo + qoff + 32);

  const int lwv = lw[b*L_ + ig];
  const int fwv = fw[b*L_ + ig];
  const bool kpi = kpA[b*L_ + ig] != 0;
  const bool anyk = kpany[b] != 0;

  const size_t kbase = (size_t)bh*L_*HD_;
  const size_t vbase = (size_t)bh*HD_*L_;
  const unsigned char* jmb = jmask + (size_t)b*L_;

  f32x4 z4 = {0.f, 0.f, 0.f, 0.f};
  f32x4 o[4]; o[0]=z4; o[1]=z4; o[2]=z4; o[3]=z4;   // o[t2][r]: O[i_loc=4*l4+r][d=16*t2+l15]
  float mrow = -3e38f, lrow = 0.f;

  for (int jj = 0; jj < 8; ++jj) {
    const int j0 = (sp*8 + jj)*64;
    // ---- S^T = K x Q^T (bf16x3): s[t][r] = S[ig][j0 + 16t + 4*l4 + r] ----
    f32x4 s[4]; s[0]=z4; s[1]=z4; s[2]=z4; s[3]=z4;
    #pragma unroll
    for (int t = 0; t < 4; ++t) {
      const size_t koff = kbase + (size_t)(j0 + 16*t + l15)*HD_ + l4*8;
      bf16x8 kh0 = *(const bf16x8*)(khi + koff);
      bf16x8 kh1 = *(const bf16x8*)(khi + koff + 32);
      bf16x8 kl0 = *(const bf16x8*)(klo + koff);
      bf16x8 kl1 = *(const bf16x8*)(klo + koff + 32);
      s[t] = __builtin_amdgcn_mfma_f32_16x16x32_bf16(kh0, qh0, s[t], 0, 0, 0);
      s[t] = __builtin_amdgcn_mfma_f32_16x16x32_bf16(kh1, qh1, s[t], 0, 0, 0);
      s[t] = __builtin_amdgcn_mfma_f32_16x16x32_bf16(kh0, ql0, s[t], 0, 0, 0);
      s[t] = __builtin_amdgcn_mfma_f32_16x16x32_bf16(kh1, ql1, s[t], 0, 0, 0);
      s[t] = __builtin_amdgcn_mfma_f32_16x16x32_bf16(kl0, qh0, s[t], 0, 0, 0);
      s[t] = __builtin_amdgcn_mfma_f32_16x16x32_bf16(kl1, qh1, s[t], 0, 0, 0);
    }
    // ---- mask ----
    #pragma unroll
    for (int t = 0; t < 4; ++t) {
      const unsigned jm = *(const unsigned*)(jmb + j0 + 16*t + 4*l4);
      #pragma unroll
      for (int r = 0; r < 4; ++r) {
        int j = j0 + 16*t + 4*l4 + r;
        unsigned fl = jm >> (8*r);
        bool allow = (j <= ig) ? (j >= ig - lwv) : (j <= ig + fwv);
        allow = allow || ((fl & 2u) != 0u);
        if (anyk) allow = allow || kpi || ((fl & 1u) != 0u);
        else      allow = allow || (j==0) || (j==511) || (j==1023) || (j==1535) || (j==2047);
        if (!allow) s[t][r] = -1e9f;
      }
    }
    // ---- online softmax over row ig (partners: lanes ^16, ^32) ----
    float tm = fmaxf(
        fmaxf(fmaxf(fmaxf(s[0][0],s[0][1]), fmaxf(s[0][2],s[0][3])),
              fmaxf(fmaxf(s[1][0],s[1][1]), fmaxf(s[1][2],s[1][3]))),
        fmaxf(fmaxf(fmaxf(s[2][0],s[2][1]), fmaxf(s[2][2],s[2][3])),
              fmaxf(fmaxf(s[3][0],s[3][1]), fmaxf(s[3][2],s[3][3]))));
    tm = fmaxf(tm, __shfl_xor(tm, 16));
    tm = fmaxf(tm, __shfl_xor(tm, 32));
    const float mnew = fmaxf(mrow, tm);
    const float sc = __expf(mrow - mnew);
    float rs = 0.f;
    #pragma unroll
    for (int t = 0; t < 4; ++t) {
      #pragma unroll
      for (int r = 0; r < 4; ++r) { float p = __expf(s[t][r] - mnew); s[t][r] = p; rs += p; }
    }
    rs += __shfl_xor(rs, 16);
    rs += __shfl_xor(rs, 32);
    lrow = lrow*sc + rs;
    mrow = mnew;
    // ---- rescale O (scale for row 4*l4+r lives in lane 4*l4+r) ----
    #pragma unroll
    for (int r = 0; r < 4; ++r) {
      float scR = __shfl(sc, 4*l4 + r);
      o[0][r] *= scR; o[1][r] *= scR; o[2][r] *= scR; o[3][r] *= scR;
    }
    // ---- pack P hi/lo into A-frags: slot(l4,e) <-> j = 32c + 16*(e>>2) + 4*l4 + (e&3) ----
    bf16x8 ph0, ph1, pl0, pl1;
    #pragma unroll
    for (int e = 0; e < 8; ++e) {
      {
        float pv = s[e>>2][e&3];
        short hi = f2bf(pv);
        ph0[e] = hi; pl0[e] = f2bf(pv - bf2f(hi));
      }
      {
        float pv = s[2 + (e>>2)][e&3];
        short hi = f2bf(pv);
        ph1[e] = hi; pl1[e] = f2bf(pv - bf2f(hi));
      }
    }
    // ---- PV (bf16x3): o[t2] += P x V, V fragments use the same slot->j map ----
    #pragma unroll
    for (int t2 = 0; t2 < 4; ++t2) {
      const size_t voff = vbase + (size_t)(16*t2 + l15)*L_ + j0 + 4*l4;
      s16x4 a0 = *(const s16x4*)(vhi + voff);
      s16x4 a1 = *(const s16x4*)(vhi + voff + 16);
      s16x4 a2 = *(const s16x4*)(vhi + voff + 32);
      s16x4 a3 = *(const s16x4*)(vhi + voff + 48);
      bf16x8 vh0 = __builtin_shufflevector(a0, a1, 0,1,2,3,4,5,6,7);
      bf16x8 vh1 = __builtin_shufflevector(a2, a3, 0,1,2,3,4,5,6,7);
      s16x4 b0 = *(const s16x4*)(vlo + voff);
      s16x4 b1 = *(const s16x4*)(vlo + voff + 16);
      s16x4 b2 = *(const s16x4*)(vlo + voff + 32);
      s16x4 b3 = *(const s16x4*)(vlo + voff + 48);
      bf16x8 vl0 = __builtin_shufflevector(b0, b1, 0,1,2,3,4,5,6,7);
      bf16x8 vl1 = __builtin_shufflevector(b2, b3, 0,1,2,3,4,5,6,7);
      o[t2] = __builtin_amdgcn_mfma_f32_16x16x32_bf16(ph0, vh0, o[t2], 0, 0, 0);
      o[t2] = __builtin_amdgcn_mfma_f32_16x16x32_bf16(ph1, vh1, o[t2], 0, 0, 0);
      o[t2] = __builtin_amdgcn_mfma_f32_16x16x32_bf16(ph0, vl0, o[t2], 0, 0, 0);
      o[t2] = __builtin_amdgcn_mfma_f32_16x16x32_bf16(ph1, vl1, o[t2], 0, 0, 0);
      o[t2] = __builtin_amdgcn_mfma_f32_16x16x32_bf16(pl0, vh0, o[t2], 0, 0, 0);
      o[t2] = __builtin_amdgcn_mfma_f32_16x16x32_bf16(pl1, vh1, o[t2], 0, 0, 0);
    }
  }
  // ---- stash partials in LDS ----
  #pragma unroll
  for (int t2 = 0; t2 < 4; ++t2)
    #pragma unroll
    for (int r = 0; r < 4; ++r)
      lds_o[sp][16*wq + 4*l4 + r][16*t2 + l15] = o[t2][r];
  if (l4 == 0) lds_ml[sp][16*wq + l15] = make_float2(mrow, lrow);
  __syncthreads();

  // ---- merge 4 splits + gate multiply + emit ctx*gate hi/lo ----
  {
    const int row = tid >> 4;          // 0..31
    const int d   = (tid & 15) * 4;    // 0..60
    float2 ml0 = lds_ml[0][row], ml1 = lds_ml[1][row], ml2 = lds_ml[2][row], ml3 = lds_ml[3][row];
    float M = fmaxf(fmaxf(ml0.x, ml1.x), fmaxf(ml2.x, ml3.x));
    float w0 = __expf(ml0.x - M), w1 = __expf(ml1.x - M), w2 = __expf(ml2.x - M), w3 = __expf(ml3.x - M);
    float Ls = w0*ml0.y + w1*ml1.y + w2*ml2.y + w3*ml3.y;
    float4 o0 = *(const float4*)&lds_o[0][row][d];
    float4 o1 = *(const float4*)&lds_o[1][row][d];
    float4 o2 = *(const float4*)&lds_o[2][row][d];
    float4 o3 = *(const float4*)&lds_o[3][row][d];
    float invL = 1.0f / Ls;
    float4 res;
    res.x = (w0*o0.x + w1*o1.x + w2*o2.x + w3*o3.x) * invL;
    res.y = (w0*o0.y + w1*o1.y + w2*o2.y + w3*o3.y) * invL;
    res.z = (w0*o0.z + w1*o1.z + w2*o2.z + w3*o3.z) * invL;
    res.w = (w0*o0.w + w1*o1.w + w2*o2.w + w3*o3.w) * invL;
    const int m = b*L_ + it*32 + row;
    const int col = h*HD_ + d;
    float4 g4 = *(const float4*)(gateb + (size_t)m*D_ + col);
    res.x *= g4.x; res.y *= g4.y; res.z *= g4.z; res.w *= g4.w;
    ushort4 uh, ul;
    short h0 = f2bf(res.x), h1 = f2bf(res.y), h2 = f2bf(res.z), h3 = f2bf(res.w);
    uh.x = (ushort)h0; uh.y = (ushort)h1; uh.z = (ushort)h2; uh.w = (ushort)h3;
    ul.x = (ushort)f2bf(res.x - bf2f(h0)); ul.y = (ushort)f2bf(res.y - bf2f(h1));
    ul.z = (ushort)f2bf(res.z - bf2f(h2)); ul.w = (ushort)f2bf(res.w - bf2f(h3));
    *(ushort4*)(cgh + (size_t)m*D_ + col) = uh;
    *(ushort4*)(cgl + (size_t)m*D_ + col) = ul;
  }
}

extern "C" void kernel_launch(void* const* d_in, const int* in_sizes, int n_in,
                              void* d_out, int out_size, void* d_ws, size_t ws_size,
                              hipStream_t stream) {
  (void)in_sizes; (void)n_in; (void)out_size; (void)ws_size;
  const float* x    = (const float*)d_in[0];
  const float* Wq   = (const float*)d_in[1];  const float* bq = (const float*)d_in[2];
  const float* Wk   = (const float*)d_in[3];  const float* bk = (const float*)d_in[4];
  const float* Wv   = (const float*)d_in[5];  const float* bv = (const float*)d_in[6];
  const float* Wo   = (const float*)d_in[7];  const float* bo = (const float*)d_in[8];
  const float* Wg   = (const float*)d_in[9];  const float* bg = (const float*)d_in[10];
  const float* lnqg = (const float*)d_in[11]; const float* lnqb = (const float*)d_in[12];
  const float* lnkg = (const float*)d_in[13]; const float* lnkb = (const float*)d_in[14];
  const float* lnvg = (const float*)d_in[15]; const float* lnvb = (const float*)d_in[16];
  float* out = (float*)d_out;

  float* Wbase = (float*)d_ws;
  size_t off = 0;
  auto alloc = [&](size_t n) { float* p = Wbase + off; off += n; return p; };
  const size_t BLD = (size_t)B_*L_*D_, DD = (size_t)D_*D_;
  float* gateb = alloc(BLD);
  ushort* qhi = (ushort*)alloc(BLD/2);  ushort* qlo = (ushort*)alloc(BLD/2);
  ushort* khi = (ushort*)alloc(BLD/2);  ushort* klo = (ushort*)alloc(BLD/2);
  ushort* vhi = (ushort*)alloc(BLD/2);  ushort* vlo = (ushort*)alloc(BLD/2);
  ushort* cgh = (ushort*)alloc(BLD/2);  ushort* cgl = (ushort*)alloc(BLD/2);
  ushort* Wth[5]; ushort* Wtl[5];
  for (int i = 0; i < 5; ++i) { Wth[i] = (ushort*)alloc(DD/2); Wtl[i] = (ushort*)alloc(DD/2); }
  float* biasq = alloc(512); float* biask = alloc(512); float* biasv = alloc(512);
  float* colmean = alloc(B_*D_); float* colssq = alloc(B_*D_); float* coldiff = alloc(B_*D_);
  float* pcs = alloc(32*B_*D_);  float* pcq = alloc(32*B_*D_);
  float* rowmean = alloc(B_*L_); float* rowrstd = alloc(B_*L_);
  float* impre = alloc(B_*L_);   float* tipA = alloc(B_*L_);   float* dmeanA = alloc(B_*L_);
  float* d1A = alloc(B_*L_);     float* magA = alloc(B_*L_);   float* wvmA = alloc(B_*L_);
  float* impG = alloc(B_*L_);
  float* bstats = alloc(32);
  int* lw     = (int*)alloc(B_*L_);
  int* fw     = (int*)alloc(B_*L_);
  int* kpA    = (int*)alloc(B_*L_);
  int* kpany  = (int*)alloc(16);
  unsigned char* jmaskA = (unsigned char*)alloc(B_*L_/4);

  TPtrs tp;
  tp.in[0] = Wq; tp.gv[0] = lnqg; tp.oh[0] = Wth[0]; tp.ol[0] = Wtl[0];
  tp.in[1] = Wk; tp.gv[1] = lnkg; tp.oh[1] = Wth[1]; tp.ol[1] = Wtl[1];
  tp.in[2] = Wv; tp.gv[2] = lnvg; tp.oh[2] = Wth[2]; tp.ol[2] = Wtl[2];
  tp.in[3] = Wg; tp.gv[3] = nullptr; tp.oh[3] = Wth[3]; tp.ol[3] = Wtl[3];
  tp.in[4] = Wo; tp.gv[4] = nullptr; tp.oh[4] = Wth[4]; tp.ol[4] = Wtl[4];
  k_transpose5<<<dim3(16,16,5), dim3(32,8), 0, stream>>>(tp);

  k_biasfold<<<2, 256, 0, stream>>>(Wq, lnqb, bq, biasq);
  k_biasfold<<<2, 256, 0, stream>>>(Wk, lnkb, bk, biask);
  k_biasfold<<<2, 256, 0, stream>>>(Wv, lnvb, bv, biasv);

  k_colstats_a<<<128, 256, 0, stream>>>(x, pcs, pcq);
  k_colstats_b<<<4, 256, 0, stream>>>(x, pcs, pcq, colmean, colssq, coldiff);
  k_rowstats<<<B_*L_, 256, 0, stream>>>(x, colmean, rowmean, rowrstd, impre, tipA, dmeanA, d1A, magA, wvmA);
  k_batchstats<<<B_, 256, 0, stream>>>(colssq, coldiff, impre, tipA, dmeanA, bstats, kpany);
  k_finalize<<<(B_*L_)/256, 256, 0, stream>>>(impre, tipA, dmeanA, magA, d1A, wvmA, bstats, lw, fw, kpA, kpany, impG);
  k_topk<<<dim3(4, B_), 64, 0, stream>>>(impG, kpA, jmaskA);

  // gate: A = x (no LN), sigmoid -> fp32
  k_gemm_mfma<<<dim3(128,8), 256, 0, stream>>>(x, nullptr, nullptr, nullptr, nullptr,
      Wth[3], Wtl[3], bg, gateb, nullptr, nullptr, 1, 1.0f);
  // q/k/v: A = (x-m)*rstd (LN folded into weights/bias)
  k_gemm_mfma<<<dim3(128,8), 256, 0, stream>>>(x, nullptr, nullptr, rowmean, rowrstd,
      Wth[0], Wtl[0], biasq, nullptr, qhi, qlo, 2, 0.125f);
  k_gemm_mfma<<<dim3(128,8), 256, 0, stream>>>(x, nullptr, nullptr, rowmean, rowrstd,
      Wth[1], Wtl[1], biask, nullptr, khi, klo, 3, 1.0f);
  k_gemm_mfma<<<dim3(128,8), 256, 0, stream>>>(x, nullptr, nullptr, rowmean, rowrstd,
      Wth[2], Wtl[2], biasv, nullptr, vhi, vlo, 4, 1.0f);

  k_attn<<<dim3(64, H_, B_), 512, 0, stream>>>(qhi, qlo, khi, klo, vhi, vlo,
      lw, fw, kpA, jmaskA, kpany, gateb, cgh, cgl);

  // out: A = ctx*gate (bf16 hi/lo from attn merge)
  k_gemm_mfma<<<dim3(128,8), 256, 0, stream>>>(nullptr, cgh, cgl, nullptr, nullptr,
      Wth[4], Wtl[4], bo, out, nullptr, nullptr, 0, 1.0f);
}